// Round 2
// baseline (1149.921 us; speedup 1.0000x reference)
//
#include <hip/hip_runtime.h>
#include <math.h>

#define DD 256
#define DHALF 128.0f

__global__ __launch_bounds__(256) void slice_extract_phase_kernel(
    const float* __restrict__ vol,   // (B, 2, D, D, D) float32
    const float* __restrict__ rot,   // (B, 3, 3) float32
    const float* __restrict__ trans, // (B, 2) float32
    float* __restrict__ out)         // (B, 2, D, D) float32
{
    const int tid = blockIdx.x * blockDim.x + threadIdx.x;
    const int j = tid & (DD - 1);
    const int i = (tid >> 8) & (DD - 1);
    const int b = tid >> 16;

    // Rotation: need columns 0 and 1 of R[b] (base z == 0).
    const float r00 = rot[b * 9 + 0];
    const float r01 = rot[b * 9 + 1];
    const float r10 = rot[b * 9 + 3];
    const float r11 = rot[b * 9 + 4];
    const float r20 = rot[b * 9 + 6];
    const float r21 = rot[b * 9 + 7];

    // Output index i corresponds to reference gx (w axis), j to gy (h axis)
    // because of the transpose(proj, (0,1,3,2)).
    const float px = (float)i - DHALF;
    const float py = (float)j - DHALF;

    float x = fmaf(r00, px, fmaf(r01, py, DHALF));
    float y = fmaf(r10, px, fmaf(r11, py, DHALF));
    float z = fmaf(r20, px, fmaf(r21, py, DHALF));

    // clamp to [0, D-1]
    x = fminf(fmaxf(x, 0.0f), 255.0f);
    y = fminf(fmaxf(y, 0.0f), 255.0f);
    z = fminf(fmaxf(z, 0.0f), 255.0f);

    const float x0f = floorf(x), y0f = floorf(y), z0f = floorf(z);
    const float fx = x - x0f, fy = y - y0f, fz = z - z0f;
    const int x0 = (int)x0f, y0 = (int)y0f, z0 = (int)z0f;
    const int x1 = min(x0 + 1, DD - 1);
    const int y1 = min(y0 + 1, DD - 1);
    const int z1 = min(z0 + 1, DD - 1);

    const float gx0 = 1.0f - fx, gy0 = 1.0f - fy, gz0 = 1.0f - fz;
    const float w000 = gz0 * gy0 * gx0;
    const float w001 = gz0 * gy0 * fx;
    const float w010 = gz0 * fy * gx0;
    const float w011 = gz0 * fy * fx;
    const float w100 = fz * gy0 * gx0;
    const float w101 = fz * gy0 * fx;
    const float w110 = fz * fy * gx0;
    const float w111 = fz * fy * fx;

    const size_t plane = (size_t)DD * DD;           // 65536
    const size_t cstride = plane * DD;              // 256^3
    const float* v0 = vol + (size_t)b * 2 * cstride;
    const float* v1 = v0 + cstride;

    const size_t z0o = (size_t)z0 * plane, z1o = (size_t)z1 * plane;
    const size_t y0o = (size_t)y0 * DD, y1o = (size_t)y1 * DD;

    const size_t o00 = z0o + y0o;  // z0,y0
    const size_t o01 = z0o + y1o;  // z0,y1
    const size_t o10 = z1o + y0o;  // z1,y0
    const size_t o11 = z1o + y1o;  // z1,y1

    float re =
        v0[o00 + x0] * w000 + v0[o00 + x1] * w001 +
        v0[o01 + x0] * w010 + v0[o01 + x1] * w011 +
        v0[o10 + x0] * w100 + v0[o10 + x1] * w101 +
        v0[o11 + x0] * w110 + v0[o11 + x1] * w111;
    float im =
        v1[o00 + x0] * w000 + v1[o00 + x1] * w001 +
        v1[o01 + x0] * w010 + v1[o01 + x1] * w011 +
        v1[o10 + x0] * w100 + v1[o10 + x1] * w101 +
        v1[o11 + x0] * w110 + v1[o11 + x1] * w111;

    re *= 16.0f;   // sqrt(256)
    im *= 16.0f;

    // Phase shift: t0 = -trans[b,1]*128, t1 = -trans[b,0]*128
    const float t0 = -trans[b * 2 + 1] * DHALF;
    const float t1 = -trans[b * 2 + 0] * DHALF;
    const float ki = (float)i - DHALF;
    const float kj = (float)j - DHALF;
    const float ang = (-2.0f * (float)M_PI / 256.0f) * (t0 * ki + t1 * kj);

    float sn, cs;
    sincosf(ang, &sn, &cs);   // accurate version: |ang| can reach ~800 rad

    const size_t ob = (size_t)b * 2 * plane + (size_t)i * DD + j;
    out[ob]         = re * cs - im * sn;
    out[ob + plane] = re * sn + im * cs;
}

extern "C" void kernel_launch(void* const* d_in, const int* in_sizes, int n_in,
                              void* d_out, int out_size, void* d_ws, size_t ws_size,
                              hipStream_t stream) {
    const float* vol   = (const float*)d_in[0];
    const float* rot   = (const float*)d_in[1];
    const float* trans = (const float*)d_in[2];
    float* out = (float*)d_out;

    const int B = in_sizes[0] / (2 * DD * DD * DD);   // 8
    const int total = B * DD * DD;                    // 524288 threads
    dim3 block(256);
    dim3 grid(total / 256);
    slice_extract_phase_kernel<<<grid, block, 0, stream>>>(vol, rot, trans, out);
}